// Round 7
// baseline (8469.272 us; speedup 1.0000x reference)
//
#include <hip/hip_runtime.h>
#include <hip/hip_bf16.h>

// MatchLSTM boundary-pointer model on MI355X (gfx950).
// B=32 T=400 J=30 V=50000 D=150 H=150 L=2. Output [B,2,401].
//
// Round 7: round 6 fit the 128-reg law (VGPR=116, no spill) but steps are
// ~13k cyc: latency-bound (VALUBusy ~32% of active CUs) — dependent LDS
// broadcast chains + barriers can't be hidden at 2 waves/SIMD. Fix: batch-
// multiplex the scans. Weights are batch-shared, so 2 batches per match
// block / 4 per GRU block turn every h-broadcast + weight register into
// 2-4 FMA streams (phase A goes issue-bound) and amortize barriers,
// softmax, and combine. LDS re-budgeted to 163,520 B; regs ~120 <= 128.

namespace {

constexpr int NBATCH = 32;
constexpr int TLEN   = 400;
constexpr int JQ     = 30;
constexpr int T1     = 401;

__device__ __forceinline__ float sigm(float x){ return 1.f/(1.f+__expf(-x)); }
__device__ __forceinline__ float tanh_f(float x){
  float e = __expf(-2.f*fabsf(x));
  float t = (1.f-e)/(1.f+e);
  return x < 0.f ? -t : t;
}
__device__ __forceinline__ float bf2f(unsigned short u){
  union { unsigned int i; float f; } c; c.i = ((unsigned int)u)<<16; return c.f;
}

#define NW 29
struct WDesc { const void* src[NW]; int off[NW+1]; };

__global__ void sniff_kernel(const unsigned int* __restrict__ bits, int* __restrict__ flag){
  __shared__ int cnt;
  if (threadIdx.x==0) cnt = 0;
  __syncthreads();
  int hit = 0;
  #pragma unroll
  for (int i=0;i<4;i++){
    unsigned int w = bits[threadIdx.x*4+i];
    unsigned int b = (w>>8)&0x7Fu;
    if (b==0u || (b>=0x38u && b<=0x3Fu)) hit++;
  }
  atomicAdd(&cnt, hit);
  __syncthreads();
  if (threadIdx.x==0) *flag = (cnt > 768) ? 1 : 0;
}

__global__ void convert_weights_kernel(WDesc d, float* __restrict__ out, const int* __restrict__ flag){
  const int isbf = *flag;
  const int total = d.off[NW];
  for (int e = blockIdx.x*blockDim.x+threadIdx.x; e < total; e += gridDim.x*blockDim.x){
    int j = 0;
    while (e >= d.off[j+1]) j++;
    int i = e - d.off[j];
    out[e] = isbf ? bf2f(((const unsigned short*)d.src[j])[i])
                  : ((const float*)d.src[j])[i];
  }
}

__global__ void padrows_kernel(const float* __restrict__ src, float* __restrict__ dst,
                               int rows, int cols, int ldd){
  int i = blockIdx.x*blockDim.x+threadIdx.x;
  if (i >= rows*ldd) return;
  int r = i/ldd, c = i-r*ldd;
  dst[i] = (c<cols) ? src[(size_t)r*cols+c] : 0.f;
}

// Wcat[600][152]: rows<450 = Whh; rows>=450: Wcat[450+k][i] = Wr[i][k]
__global__ void build_wcat_kernel(const float* __restrict__ Whh, const float* __restrict__ Wr,
                                  float* __restrict__ Wcat){
  int i = blockIdx.x*blockDim.x+threadIdx.x;
  if (i >= 600*152) return;
  int r = i/152, c = i-r*152;
  float v = 0.f;
  if (c < 150){
    if (r < 450) v = Whh[(size_t)r*150+c];
    else         v = Wr[(size_t)c*150 + (r-450)];
  }
  Wcat[i] = v;
}

// s2q[(q*512+r)*4+p] = Wcat[r*152+104+4q+p]  (q<12, r<512)
// ext[(q*88+i)*4+p]  = Wcat[(512+i)*152+4q+p] (q<38, i<88)
__global__ void build_msplit_kernel(const float* __restrict__ Wcat,
                                    float* __restrict__ s2q, float* __restrict__ ext){
  int i = blockIdx.x*blockDim.x+threadIdx.x;
  if (i < 24576){
    int q = i/2048, rem = i-q*2048, r = rem/4, p = rem-r*4;
    s2q[i] = Wcat[(size_t)r*152 + 104 + 4*q + p];
  } else if (i < 24576+13376){
    int k = i-24576;
    int q = k/352, rem = k-q*352, ii = rem/4, p = rem-ii*4;
    ext[k] = Wcat[(size_t)(512+ii)*152 + 4*q + p];
  }
}

// s2q[(q*452+r)*4+p] = (r<450) ? Wpad[r*152+104+4q+p] : 0   (q<12, r<452)
__global__ void build_gsplit_kernel(const float* __restrict__ Wpad, float* __restrict__ s2q){
  int i = blockIdx.x*blockDim.x+threadIdx.x;
  if (i >= 12*452*4) return;
  int q = i/1808, rem = i-q*1808, r = rem/4, p = rem-r*4;
  s2q[i] = (r<450) ? Wpad[(size_t)r*152 + 104 + 4*q + p] : 0.f;
}

// ---- generic row-tiled projection; out stride ldo (zero-fill K..ldo)
__global__ __launch_bounds__(512) void rowproj_kernel(
    const float* __restrict__ Xrows,
    const int* __restrict__ gather, const void* __restrict__ Etab, const int* __restrict__ bfflag,
    const float* __restrict__ W, const float* __restrict__ bias,
    float* __restrict__ out, int rows, int K, int inner, int mode, int ldw, int offw, int ldo)
{
  __shared__ float xs[8][304];
  const int r0 = blockIdx.x*8;
  int nr = rows - r0; if (nr > 8) nr = 8;
  if (nr <= 0) return;
  const int isbf = gather ? *bfflag : 0;
  for (int e = threadIdx.x; e < nr*inner; e += blockDim.x){
    int r = e/inner, i = e - r*inner;
    float v;
    if (gather){
      size_t base = (size_t)gather[r0+r]*inner + i;
      v = isbf ? bf2f(((const unsigned short*)Etab)[base]) : ((const float*)Etab)[base];
    } else {
      v = Xrows[(size_t)(r0+r)*inner + i];
    }
    xs[r][i] = v;
  }
  __syncthreads();
  for (int k = threadIdx.x; k < ldo; k += blockDim.x){
    if (k < K){
      float b0 = bias ? bias[k] : 0.f;
      float acc[8];
      #pragma unroll
      for (int r=0;r<8;r++) acc[r] = b0;
      if (mode==0){
        for (int i=0;i<inner;i++){
          float wv = W[(size_t)i*ldw + k];
          #pragma unroll
          for (int r=0;r<8;r++) acc[r] += xs[r][i]*wv;
        }
      } else {
        const float* wr = W + (size_t)k*ldw + offw;
        for (int i=0;i<inner;i++){
          float wv = wr[i];
          #pragma unroll
          for (int r=0;r<8;r++) acc[r] += xs[r][i]*wv;
        }
      }
      for (int r=0;r<nr;r++) out[(size_t)(r0+r)*ldo + k] = acc[r];
    } else {
      for (int r=0;r<nr;r++) out[(size_t)(r0+r)*ldo + k] = 0.f;
    }
  }
}

// ---- 26-quad register macros ---------------------------------------------
#define R26(M) M(0) M(1) M(2) M(3) M(4) M(5) M(6) M(7) M(8) M(9) M(10) M(11) \
               M(12) M(13) M(14) M(15) M(16) M(17) M(18) M(19) M(20) M(21) \
               M(22) M(23) M(24) M(25)
#define DECW(i) float4 w##i;
#define LDW(i)  w##i = wrow4[i];
// 2-batch FMA (match)
#define FMAW2(i) { float4 p = h04[i]; float4 r2 = h14[i]; \
  a0 = fmaf(p.x,  w##i.x, a0); a1 = fmaf(p.y,  w##i.y, a1); \
  a0 = fmaf(p.z,  w##i.z, a0); a1 = fmaf(p.w,  w##i.w, a1); \
  c0 = fmaf(r2.x, w##i.x, c0); c1 = fmaf(r2.y, w##i.y, c1); \
  c0 = fmaf(r2.z, w##i.z, c0); c1 = fmaf(r2.w, w##i.w, c1); }
// 4-batch FMA (gru)
#define FMAW4(i) { float4 p0=hA4[i], p1=hB4[i], p2=hC4[i], p3=hD4[i]; \
  a0=fmaf(p0.x,w##i.x,a0); a0=fmaf(p0.y,w##i.y,a0); a0=fmaf(p0.z,w##i.z,a0); a0=fmaf(p0.w,w##i.w,a0); \
  a1=fmaf(p1.x,w##i.x,a1); a1=fmaf(p1.y,w##i.y,a1); a1=fmaf(p1.z,w##i.z,a1); a1=fmaf(p1.w,w##i.w,a1); \
  a2=fmaf(p2.x,w##i.x,a2); a2=fmaf(p2.y,w##i.y,a2); a2=fmaf(p2.z,w##i.z,a2); a2=fmaf(p2.w,w##i.w,a2); \
  a3=fmaf(p3.x,w##i.x,a3); a3=fmaf(p3.y,w##i.y,a3); a3=fmaf(p3.z,w##i.z,a3); a3=fmaf(p3.w,w##i.w,a3); }

// ---- merged GRU encoder scan, 4 batches/block.
// blocks 0..7: context batches 4*blk.. ; blocks 8..15: query batches.
__global__ __launch_bounds__(512) void gru_scan_kernel(
    const float* __restrict__ gi0, const float* __restrict__ Wp0,
    const float* __restrict__ s2q0, const float* __restrict__ bh0,
    float* __restrict__ H0, int S0,
    const float* __restrict__ gi1, const float* __restrict__ Wp1,
    const float* __restrict__ s2q1, const float* __restrict__ bh1,
    float* __restrict__ H1, int S1)
{
  const int blk = blockIdx.x;
  const float* gi; const float* Wpad; const float* s2qG; const float* bh; float* Hs; int S;
  if (blk < 8){ int b0 = 4*blk;
    gi = gi0 + (size_t)b0*S0*450;  Wpad = Wp0; s2qG = s2q0; bh = bh0;
    Hs = H0 + (size_t)b0*S0*150;   S = S0;
  } else { int b0 = 4*(blk-8);
    gi = gi1 + (size_t)b0*S1*450;  Wpad = Wp1; s2qG = s2q1; bh = bh1;
    Hs = H1 + (size_t)b0*S1*150;   S = S1;
  }
  __shared__ float4 s2W[5424];               // [12][452], 86,784 B
  __shared__ __align__(16) float hg[4][152]; // 2,432
  __shared__ float ghB[4][452];              // 7,232
  const int tid = threadIdx.x;

  R26(DECW)
  float br;
  {
    const float4* wrow4 = (const float4*)(Wpad + (size_t)((tid<450)?tid:0)*152);
    R26(LDW)
    br = (tid<450) ? bh[tid] : 0.f;
  }
  for (int e=tid; e<5424; e+=512) s2W[e] = ((const float4*)s2qG)[e];
  if (tid < 152){ hg[0][tid]=0.f; hg[1][tid]=0.f; hg[2][tid]=0.f; hg[3][tid]=0.f; }
  __syncthreads();
  const float4* hA4 = (const float4*)hg[0];
  const float4* hB4 = (const float4*)hg[1];
  const float4* hC4 = (const float4*)hg[2];
  const float4* hD4 = (const float4*)hg[3];

  const int bb1 = tid/150;            // task1: covers (bb,k) for all 512 tids
  const int k1  = tid - 150*bb1;      // tid>=450 -> bb=3, k=0..61

  for (int t=0;t<S;t++){
    // prefetch gi for task1 (consumed after b1)
    const float* gg = gi + ((size_t)(bb1*S) + t)*450 + k1;
    float g0 = gg[0], g1 = gg[150], g2 = gg[300];

    if (tid < 450){
      float a0=br, a1=br, a2=br, a3=br;
      R26(FMAW4)
      #pragma unroll
      for (int q=0;q<12;q++){
        float4 wq = s2W[q*452+tid];
        float4 p0=hA4[26+q], p1=hB4[26+q], p2=hC4[26+q], p3=hD4[26+q];
        a0=fmaf(p0.x,wq.x,a0); a0=fmaf(p0.y,wq.y,a0); a0=fmaf(p0.z,wq.z,a0); a0=fmaf(p0.w,wq.w,a0);
        a1=fmaf(p1.x,wq.x,a1); a1=fmaf(p1.y,wq.y,a1); a1=fmaf(p1.z,wq.z,a1); a1=fmaf(p1.w,wq.w,a1);
        a2=fmaf(p2.x,wq.x,a2); a2=fmaf(p2.y,wq.y,a2); a2=fmaf(p2.z,wq.z,a2); a2=fmaf(p2.w,wq.w,a2);
        a3=fmaf(p3.x,wq.x,a3); a3=fmaf(p3.y,wq.y,a3); a3=fmaf(p3.z,wq.z,a3); a3=fmaf(p3.w,wq.w,a3);
      }
      ghB[0][tid]=a0; ghB[1][tid]=a1; ghB[2][tid]=a2; ghB[3][tid]=a3;
    }
    __syncthreads();   // b1

    // E task1 (all 512 threads)
    {
      float r = sigm(g0 + ghB[bb1][k1]);
      float z = sigm(g1 + ghB[bb1][150+k1]);
      float n = tanh_f(g2 + r*ghB[bb1][300+k1]);
      float hn = (1.f-z)*n + z*hg[bb1][k1];
      hg[bb1][k1] = hn;
      Hs[((size_t)(bb1*S) + t)*150 + k1] = hn;
    }
    // E task2 (bb=3, k=62..149) on tids 0..87
    if (tid < 88){
      int k2 = 62 + tid;
      const float* g2p = gi + ((size_t)(3*S) + t)*450 + k2;
      float r = sigm(g2p[0]   + ghB[3][k2]);
      float z = sigm(g2p[150] + ghB[3][150+k2]);
      float n = tanh_f(g2p[300] + r*ghB[3][300+k2]);
      float hn = (1.f-z)*n + z*hg[3][k2];
      hg[3][k2] = hn;
      Hs[((size_t)(3*S) + t)*150 + k2] = hn;
    }
    __syncthreads();   // b2
  }
}

__global__ void zero_hr0_kernel(float* __restrict__ Hr){
  int idx = blockIdx.x*blockDim.x + threadIdx.x;
  if (idx < NBATCH*300){
    int b = idx/300, k = idx - 300*b;
    Hr[(size_t)b*T1*300 + k] = 0.f;
  }
}

// ---- match scan: 2 batches per block; grid (16, 2dirs); 512 threads.
__global__ __launch_bounds__(512) void match_scan_kernel(
    const float* __restrict__ pWp,   // [B,T,152]
    const float* __restrict__ whq,   // [B,J,152]
    const float* __restrict__ giXf,  // [B,T,452]
    const float* __restrict__ giXr,
    const float* __restrict__ Pf,    // [B,J,452]
    const float* __restrict__ Pr,
    const float* __restrict__ WcatF, const float* __restrict__ WcatR, // [600][152]
    const float* __restrict__ s2qF,  const float* __restrict__ s2qR,  // [12][512] f4
    const float* __restrict__ extF,  const float* __restrict__ extR,  // [38][88] f4
    const float* __restrict__ m_bhh, const float* __restrict__ mr_bhh,
    const float* __restrict__ wvec,  // [150]
    float* __restrict__ Hr)          // [B,401,300]
{
  const int b0  = blockIdx.x*2;
  const int dir = blockIdx.y;
  const float* giX  = dir ? giXr : giXf;
  const float* P    = dir ? Pr   : Pf;
  const float* Wcat = dir ? WcatR : WcatF;
  const float* s2qG = dir ? s2qR  : s2qF;
  const float* extG = dir ? extR  : extF;
  const float* bhh  = dir ? mr_bhh : m_bhh;

  __shared__ float4 s2W[6144];                 // 98,304
  __shared__ float4 extW[3344];                // 53,504
  __shared__ __align__(16) float h[2][152];    //  1,216
  __shared__ float ghsB[2][512];               //  4,096
  __shared__ float extPart[2][88];             //    704
  __shared__ __align__(16) float baseS[2][152];//  1,216
  __shared__ __align__(16) float gis[2][452];  //  3,616
  __shared__ float scS[2][32];                 //    256
  __shared__ __align__(16) float wlS[152];     //    608  -> 163,520 B

  const int tid  = threadIdx.x;
  const int lane = tid & 63;
  const int wv   = tid >> 6;

  R26(DECW)
  float br;
  {
    const float4* wrow4 = (const float4*)(Wcat + (size_t)tid*152);
    R26(LDW)
    br = (tid < 450) ? bhh[tid] : 0.f;
  }
  for (int e=tid; e<6144; e+=512) s2W[e]  = ((const float4*)s2qG)[e];
  for (int e=tid; e<3344; e+=512) extW[e] = ((const float4*)extG)[e];
  if (tid < 152){
    h[0][tid]=0.f; h[1][tid]=0.f;
    wlS[tid] = (tid<150) ? wvec[tid] : 0.f;
  }
  __syncthreads();
  const float4* h04 = (const float4*)h[0];
  const float4* h14 = (const float4*)h[1];

  const int extOn = (tid < 176);
  const int ebb = extOn ? (tid/88) : 0;
  const int erw = extOn ? (tid%88) : 0;
  const int pwOn = (tid >= 192 && tid < 268);
  const int pbb = pwOn ? ((tid-192)/38) : 0;
  const int pq  = pwOn ? ((tid-192)%38) : 0;
  const int dOn = (tid >= 286);
  const int dbb = dOn ? ((tid-286)/113) : 0;
  const int dq  = dOn ? ((tid-286)%113) : 0;

  for (int t=0;t<TLEN;t++){
    const int tt = dir ? (TLEN-1-t) : t;

    float4 pwv;
    if (pwOn) pwv = ((const float4*)(pWp + ((size_t)(b0+pbb)*TLEN + tt)*152))[pq];

    // A: row dots for rows 0..511, both batches
    {
      float a0=br, a1=0.f, c0=br, c1=0.f;
      R26(FMAW2)
      #pragma unroll
      for (int q=0;q<12;q++){
        float4 wq = s2W[q*512+tid];
        float4 p = h04[26+q], r2 = h14[26+q];
        a0 = fmaf(p.x, wq.x,a0); a1 = fmaf(p.y, wq.y,a1);
        a0 = fmaf(p.z, wq.z,a0); a1 = fmaf(p.w, wq.w,a1);
        c0 = fmaf(r2.x,wq.x,c0); c1 = fmaf(r2.y,wq.y,c1);
        c0 = fmaf(r2.z,wq.z,c0); c1 = fmaf(r2.w,wq.w,c1);
      }
      ghsB[0][tid] = a0+a1;
      ghsB[1][tid] = c0+c1;
    }
    // A-ext: WrT rows 62..149, one batch each
    if (extOn){
      const float4* hx = ebb ? h14 : h04;
      float e0=0.f, e1=0.f;
      #pragma unroll
      for (int q=0;q<38;q++){
        float4 wq = extW[q*88+erw];
        float4 hv = hx[q];
        e0 = fmaf(hv.x,wq.x,e0); e1 = fmaf(hv.y,wq.y,e1);
        e0 = fmaf(hv.z,wq.z,e0); e1 = fmaf(hv.w,wq.w,e1);
      }
      extPart[ebb][erw] = e0+e1;
    }
    if (pwOn) ((float4*)baseS[pbb])[pq] = pwv;
    __syncthreads();                       // b1

    // combine: base = pw + h@Wr
    if (tid < 300){
      int bb = tid/150, k = tid-150*bb;
      float wr = (k<62) ? ghsB[bb][450+k] : extPart[bb][k-62];
      baseS[bb][k] += wr;
    }
    __syncthreads();                       // b2

    // B: scores; waves 0-3 -> batch0, 4-7 -> batch1
    {
      int bb = wv>>2, jb = wv&3;
      #pragma unroll
      for (int jj=0;jj<8;jj++){
        int j = jb + 4*jj;
        float a = 0.f;
        if (j < JQ && lane < 38){
          float4 q4 = ((const float4*)(whq + ((size_t)(b0+bb)*JQ + j)*152))[lane];
          float4 b4 = ((const float4*)baseS[bb])[lane];
          float4 w4 = ((const float4*)wlS)[lane];
          a = w4.x*tanh_f(q4.x+b4.x);
          a = fmaf(w4.y, tanh_f(q4.y+b4.y), a);
          a = fmaf(w4.z, tanh_f(q4.z+b4.z), a);
          a = fmaf(w4.w, tanh_f(q4.w+b4.w), a);
        }
        #pragma unroll
        for (int off=32; off; off>>=1) a += __shfl_down(a, off);
        if (j < JQ && lane==0) scS[bb][j] = a;
      }
    }
    __syncthreads();                       // b3

    // C: softmax per batch (waves 0,1), in place
    if (tid < 128){
      int bb = wv;
      float v = (lane < JQ) ? scS[bb][lane] : -1e30f;
      float m = v;
      #pragma unroll
      for (int off=32; off; off>>=1) m = fmaxf(m, __shfl_down(m, off));
      m = __shfl(m, 0);
      float e = (lane < JQ) ? __expf(v-m) : 0.f;
      float su = e;
      #pragma unroll
      for (int off=32; off; off>>=1) su += __shfl_down(su, off);
      su = __shfl(su, 0);
      if (lane < JQ) scS[bb][lane] = e/su;
    }
    __syncthreads();                       // b4

    // D: gis = giX + attw @ P  (per-batch, 113 quads each)
    if (dOn){
      float4 acc = ((const float4*)(giX + ((size_t)(b0+dbb)*TLEN + tt)*452))[dq];
      const float4* P4 = (const float4*)(P + (size_t)(b0+dbb)*JQ*452) + dq;
      #pragma unroll 2
      for (int j=0;j<JQ;j++){
        float aw = scS[dbb][j];
        float4 p = P4[(size_t)j*113];
        acc.x = fmaf(aw,p.x,acc.x); acc.y = fmaf(aw,p.y,acc.y);
        acc.z = fmaf(aw,p.z,acc.z); acc.w = fmaf(aw,p.w,acc.w);
      }
      ((float4*)gis[dbb])[dq] = acc;
    }
    __syncthreads();                       // b5

    // E: GRU combine, write Hr
    if (tid < 300){
      int bb = tid/150, k = tid-150*bb;
      float r = sigm(gis[bb][k]     + ghsB[bb][k]);
      float z = sigm(gis[bb][150+k] + ghsB[bb][150+k]);
      float n = tanh_f(gis[bb][300+k] + r*ghsB[bb][300+k]);
      float hn = (1.f-z)*n + z*h[bb][k];
      h[bb][k] = hn;
      Hr[((size_t)(b0+bb)*T1 + (t+1))*300 + dir*150 + k] = hn;
    }
    __syncthreads();                       // b6
  }
}

// ---- pointer decoder
__global__ __launch_bounds__(512,2) void ptr_scan_kernel(
    const float* __restrict__ enc, const float* __restrict__ Hr,
    const float* __restrict__ W2, const float* __restrict__ pv,
    const float* __restrict__ dWih, const float* __restrict__ dWhh,
    const float* __restrict__ dbih, const float* __restrict__ dbhh,
    void* __restrict__ outv, const int* __restrict__ flag)
{
  const int b = blockIdx.x;
  const int tid = threadIdx.x;
  const int isbf = *flag;
  __shared__ float h[300], hW2[300], sl[T1], al[T1], c[300];
  __shared__ float gis[900], ghs[900];
  __shared__ float vl[300];
  __shared__ float red[8];
  if (tid < 300){ h[tid] = 0.f; vl[tid] = pv[tid]; }
  __syncthreads();
  for (int l=0;l<2;l++){
    if (tid < 300){
      float a0=0.f,a1=0.f;
      for (int i=0;i<300;i+=2){
        a0 += h[i]  *W2[(size_t)i*300+tid];
        a1 += h[i+1]*W2[(size_t)(i+1)*300+tid];
      }
      hW2[tid] = a0+a1;
    }
    __syncthreads();
    {
      const int wv = tid>>6, lane = tid&63;
      for (int t=wv; t<T1; t+=8){
        const float* er = enc + ((size_t)b*T1 + t)*300;
        float acc = 0.f;
        for (int k=lane; k<300; k+=64) acc += vl[k]*tanh_f(er[k] + hW2[k]);
        #pragma unroll
        for (int off=32; off; off>>=1) acc += __shfl_down(acc, off);
        if (lane==0) sl[t] = acc;
      }
    }
    __syncthreads();
    {
      float v = (tid < T1) ? sl[tid] : -1e30f;
      float m = v;
      #pragma unroll
      for (int off=32; off; off>>=1) m = fmaxf(m, __shfl_down(m, off));
      if ((tid&63)==0) red[tid>>6] = m;
      __syncthreads();
      float bm = fmaxf(fmaxf(fmaxf(red[0],red[1]),fmaxf(red[2],red[3])),
                       fmaxf(fmaxf(red[4],red[5]),fmaxf(red[6],red[7])));
      float e = (tid < T1) ? __expf(v-bm) : 0.f;
      float su = e;
      #pragma unroll
      for (int off=32; off; off>>=1) su += __shfl_down(su, off);
      __syncthreads();
      if ((tid&63)==0) red[tid>>6] = su;
      __syncthreads();
      float bs = red[0]+red[1]+red[2]+red[3]+red[4]+red[5]+red[6]+red[7];
      if (tid < T1){
        float a = e/bs;
        al[tid] = a;
        size_t oi = ((size_t)b*2 + l)*T1 + tid;
        if (isbf) ((__hip_bfloat16*)outv)[oi] = __float2bfloat16(a);
        else      ((float*)outv)[oi] = a;
      }
    }
    __syncthreads();
    if (tid < 300){
      float acc = 0.f;
      for (int t=0;t<T1;t++) acc += al[t]*Hr[((size_t)b*T1 + t)*300 + tid];
      c[tid] = acc;
    }
    __syncthreads();
    for (int k=tid; k<900; k+=blockDim.x){
      const float* wi = dWih + (size_t)k*300;
      const float* wh = dWhh + (size_t)k*300;
      float a0 = dbih[k], a1 = dbhh[k];
      for (int i=0;i<300;i++){ a0 += c[i]*wi[i]; a1 += h[i]*wh[i]; }
      gis[k] = a0; ghs[k] = a1;
    }
    __syncthreads();
    if (tid < 300){
      float r = sigm(gis[tid] + ghs[tid]);
      float z = sigm(gis[300+tid] + ghs[300+tid]);
      float n = tanh_f(gis[600+tid] + r*ghs[600+tid]);
      h[tid] = (1.f-z)*n + z*h[tid];
    }
    __syncthreads();
  }
}

} // namespace

extern "C" void kernel_launch(void* const* d_in, const int* in_sizes, int n_in,
                              void* d_out, int out_size, void* d_ws, size_t ws_size,
                              hipStream_t stream)
{
  (void)in_sizes; (void)n_in; (void)out_size; (void)ws_size;
  float* ws = (float*)d_ws;
  int* flag = (int*)d_ws;

  static const int wsz[NW] = {
    67500,67500,450,450,
    67500,67500,450,450,
    22500,22500,22500,150,150,1,
    135000,67500,450,450,
    135000,67500,450,450,
    90000,90000,300,
    270000,270000,900,900
  };
  WDesc desc;
  int cum = 0;
  for (int j=0;j<NW;j++){ desc.src[j] = d_in[3+j]; desc.off[j] = cum; cum += wsz[j]; }
  desc.off[NW] = cum;

  float* WB = ws + 16;
  const float* P_ctx_Wih = WB + desc.off[0];
  const float* P_ctx_Whh = WB + desc.off[1];
  const float* P_ctx_bih = WB + desc.off[2];
  const float* P_ctx_bhh = WB + desc.off[3];
  const float* P_q_Wih   = WB + desc.off[4];
  const float* P_q_Whh   = WB + desc.off[5];
  const float* P_q_bih   = WB + desc.off[6];
  const float* P_q_bhh   = WB + desc.off[7];
  const float* P_Wq      = WB + desc.off[8];
  const float* P_Wp      = WB + desc.off[9];
  const float* P_Wr      = WB + desc.off[10];
  const float* P_w       = WB + desc.off[11];
  const float* P_gb      = WB + desc.off[12];
  const float* P_m_Wih   = WB + desc.off[14];
  const float* P_m_Whh   = WB + desc.off[15];
  const float* P_m_bih   = WB + desc.off[16];
  const float* P_m_bhh   = WB + desc.off[17];
  const float* P_mr_Wih  = WB + desc.off[18];
  const float* P_mr_Whh  = WB + desc.off[19];
  const float* P_mr_bih  = WB + desc.off[20];
  const float* P_mr_bhh  = WB + desc.off[21];
  const float* P_W1      = WB + desc.off[22];
  const float* P_W2      = WB + desc.off[23];
  const float* P_pv      = WB + desc.off[24];
  const float* P_dWih    = WB + desc.off[25];
  const float* P_dWhh    = WB + desc.off[26];
  const float* P_dbih    = WB + desc.off[27];
  const float* P_dbhh    = WB + desc.off[28];

  size_t p = 16 + 1468512;
  float* ctxWhhP = ws + p; p += 68400;    // [450][152]
  float* qWhhP   = ws + p; p += 68400;
  float* s2qCtx  = ws + p; p += 21696;    // [12][452] f4
  float* s2qQ    = ws + p; p += 21696;
  float* WcatF   = ws + p; p += 91200;    // [600][152]
  float* WcatR   = ws + p; p += 91200;
  float* s2qF    = ws + p; p += 24576;    // [12][512] f4
  float* s2qR    = ws + p; p += 24576;
  float* extFg   = ws + p; p += 13376;    // [38][88] f4
  float* extRg   = ws + p; p += 13376;

  float* ctx_gi = ws + p; p += 5760000;   // [B,T,450]; reused as enc later
  float* q_gi   = ws + p; p += 432000;    // [B,J,450]
  float* HpB    = ws + p; p += 1920000;   // [B,T,150]
  float* HqB    = ws + p; p += 144000;    // [B,J,150]
  float* whqB   = ws + p; p += 145920;    // [B,J,152]
  float* PfB    = ws + p; p += 433920;    // [B,J,452]
  float* PrB    = ws + p; p += 433920;
  float* pWpB   = ws + p; p += 1945600;   // [B,T,152]
  float* giXfB  = ws + p; p += 5785600;   // [B,T,452]
  float* giXrB  = ws + p; p += 5785600;
  float* HrB    = ws + p; p += 3849600;   // [B,401,300]
  float* encB   = ctx_gi;                 // [B,401,300]

  // 1) dtype sniff + weight conversion + restructured layouts
  sniff_kernel<<<1,256,0,stream>>>((const unsigned int*)d_in[2], flag);
  convert_weights_kernel<<<512,256,0,stream>>>(desc, WB, flag);
  padrows_kernel<<<(450*152+255)/256,256,0,stream>>>(P_ctx_Whh, ctxWhhP, 450,150,152);
  padrows_kernel<<<(450*152+255)/256,256,0,stream>>>(P_q_Whh,   qWhhP,   450,150,152);
  build_gsplit_kernel<<<(12*452*4+255)/256,256,0,stream>>>(ctxWhhP, s2qCtx);
  build_gsplit_kernel<<<(12*452*4+255)/256,256,0,stream>>>(qWhhP,   s2qQ);
  build_wcat_kernel<<<(600*152+255)/256,256,0,stream>>>(P_m_Whh,  P_Wr, WcatF);
  build_wcat_kernel<<<(600*152+255)/256,256,0,stream>>>(P_mr_Whh, P_Wr, WcatR);
  build_msplit_kernel<<<(24576+13376+255)/256,256,0,stream>>>(WcatF, s2qF, extFg);
  build_msplit_kernel<<<(24576+13376+255)/256,256,0,stream>>>(WcatR, s2qR, extRg);

  // 2) embedding + input projections for both encoders
  rowproj_kernel<<<1600,512,0,stream>>>(nullptr,(const int*)d_in[0], d_in[2], flag,
                                        P_ctx_Wih, P_ctx_bih, ctx_gi, 12800,450,150,1,150,0,450);
  rowproj_kernel<<<120,512,0,stream>>>(nullptr,(const int*)d_in[1], d_in[2], flag,
                                       P_q_Wih, P_q_bih, q_gi, 960,450,150,1,150,0,450);

  // 3) encoder scans (4 batches/block: 8 ctx blocks + 8 query blocks)
  gru_scan_kernel<<<16,512,0,stream>>>(ctx_gi, ctxWhhP, s2qCtx, P_ctx_bhh, HpB, 400,
                                       q_gi,   qWhhP,   s2qQ,   P_q_bhh,   HqB, 30);

  // 4) Hq/Hp-dependent precomputations (padded strides)
  rowproj_kernel<<<120,192,0,stream>>>(HqB,nullptr,nullptr,nullptr, P_Wq, nullptr,
                                       whqB, 960,150,150,0,150,0,152);
  rowproj_kernel<<<120,512,0,stream>>>(HqB,nullptr,nullptr,nullptr, P_m_Wih, nullptr,
                                       PfB, 960,450,150,1,300,150,452);
  rowproj_kernel<<<120,512,0,stream>>>(HqB,nullptr,nullptr,nullptr, P_mr_Wih, nullptr,
                                       PrB, 960,450,150,1,300,150,452);
  rowproj_kernel<<<1600,192,0,stream>>>(HpB,nullptr,nullptr,nullptr, P_Wp, P_gb,
                                        pWpB, 12800,150,150,0,150,0,152);
  rowproj_kernel<<<1600,512,0,stream>>>(HpB,nullptr,nullptr,nullptr, P_m_Wih, P_m_bih,
                                        giXfB, 12800,450,150,1,300,0,452);
  rowproj_kernel<<<1600,512,0,stream>>>(HpB,nullptr,nullptr,nullptr, P_mr_Wih, P_mr_bih,
                                        giXrB, 12800,450,150,1,300,0,452);

  // 5) match scans (2 batches/block; fwd+bwd concurrent)
  zero_hr0_kernel<<<(NBATCH*300+511)/512,512,0,stream>>>(HrB);
  match_scan_kernel<<<dim3(16,2),512,0,stream>>>(pWpB, whqB, giXfB, giXrB,
                                                 PfB, PrB, WcatF, WcatR,
                                                 s2qF, s2qR, extFg, extRg,
                                                 P_m_bhh, P_mr_bhh, P_w, HrB);

  // 6) pointer decoder
  rowproj_kernel<<<1604,320,0,stream>>>(HrB,nullptr,nullptr,nullptr, P_W1, nullptr,
                                        encB, 12832,300,300,0,300,0,300);
  ptr_scan_kernel<<<32,512,0,stream>>>(encB, HrB, P_W2, P_pv,
                                       P_dWih, P_dWhh, P_dbih, P_dbhh, d_out, flag);
}

// Round 8
// 3610.442 us; speedup vs baseline: 2.3458x; 2.3458x over previous
//
#include <hip/hip_runtime.h>
#include <hip/hip_bf16.h>

// MatchLSTM boundary-pointer model on MI355X (gfx950).
// B=32 T=400 J=30 V=50000 D=150 H=150 L=2. Output [B,2,401].
//
// Round 8 = round 6 (best: 3643us) + surgical latency cuts in match_scan:
//  - giX prefetched at step start (coalesced dword/thread) -> HBM ~900cyc
//    hidden under phases A-C instead of sitting on the critical path in D.
//  - barriers 7 -> 5: combine folded into B (inline base per score lane);
//    D1+D2 merged: 452 threads each own one gis element, 30 coalesced
//    dword P reads (L2-warm), no partial-sum LDS round trip.
// Round 7 lesson (batch multiplex, -2.25x): same-wave multiplexing doubles
// the critical path; weight capacity law (65536 regs/block) forbids
// wave-split batching. Reverted.

namespace {

constexpr int NBATCH = 32;
constexpr int TLEN   = 400;
constexpr int JQ     = 30;
constexpr int T1     = 401;

__device__ __forceinline__ float sigm(float x){ return 1.f/(1.f+__expf(-x)); }
__device__ __forceinline__ float tanh_f(float x){
  float e = __expf(-2.f*fabsf(x));
  float t = (1.f-e)/(1.f+e);
  return x < 0.f ? -t : t;
}
__device__ __forceinline__ float bf2f(unsigned short u){
  union { unsigned int i; float f; } c; c.i = ((unsigned int)u)<<16; return c.f;
}

#define NW 29
struct WDesc { const void* src[NW]; int off[NW+1]; };

__global__ void sniff_kernel(const unsigned int* __restrict__ bits, int* __restrict__ flag){
  __shared__ int cnt;
  if (threadIdx.x==0) cnt = 0;
  __syncthreads();
  int hit = 0;
  #pragma unroll
  for (int i=0;i<4;i++){
    unsigned int w = bits[threadIdx.x*4+i];
    unsigned int b = (w>>8)&0x7Fu;
    if (b==0u || (b>=0x38u && b<=0x3Fu)) hit++;
  }
  atomicAdd(&cnt, hit);
  __syncthreads();
  if (threadIdx.x==0) *flag = (cnt > 768) ? 1 : 0;
}

__global__ void convert_weights_kernel(WDesc d, float* __restrict__ out, const int* __restrict__ flag){
  const int isbf = *flag;
  const int total = d.off[NW];
  for (int e = blockIdx.x*blockDim.x+threadIdx.x; e < total; e += gridDim.x*blockDim.x){
    int j = 0;
    while (e >= d.off[j+1]) j++;
    int i = e - d.off[j];
    out[e] = isbf ? bf2f(((const unsigned short*)d.src[j])[i])
                  : ((const float*)d.src[j])[i];
  }
}

__global__ void padrows_kernel(const float* __restrict__ src, float* __restrict__ dst,
                               int rows, int cols, int ldd){
  int i = blockIdx.x*blockDim.x+threadIdx.x;
  if (i >= rows*ldd) return;
  int r = i/ldd, c = i-r*ldd;
  dst[i] = (c<cols) ? src[(size_t)r*cols+c] : 0.f;
}

// Wcat[600][152]: rows<450 = Whh; rows>=450: Wcat[450+k][i] = Wr[i][k]
__global__ void build_wcat_kernel(const float* __restrict__ Whh, const float* __restrict__ Wr,
                                  float* __restrict__ Wcat){
  int i = blockIdx.x*blockDim.x+threadIdx.x;
  if (i >= 600*152) return;
  int r = i/152, c = i-r*152;
  float v = 0.f;
  if (c < 150){
    if (r < 450) v = Whh[(size_t)r*150+c];
    else         v = Wr[(size_t)c*150 + (r-450)];
  }
  Wcat[i] = v;
}

// s2q[(q*512+r)*4+p] = Wcat[r*152+104+4q+p]  (q<12, r<512)
// ext[(q*88+i)*4+p]  = Wcat[(512+i)*152+4q+p] (q<38, i<88)
__global__ void build_msplit_kernel(const float* __restrict__ Wcat,
                                    float* __restrict__ s2q, float* __restrict__ ext){
  int i = blockIdx.x*blockDim.x+threadIdx.x;
  if (i < 24576){
    int q = i/2048, rem = i-q*2048, r = rem/4, p = rem-r*4;
    s2q[i] = Wcat[(size_t)r*152 + 104 + 4*q + p];
  } else if (i < 24576+13376){
    int k = i-24576;
    int q = k/352, rem = k-q*352, ii = rem/4, p = rem-ii*4;
    ext[k] = Wcat[(size_t)(512+ii)*152 + 4*q + p];
  }
}

// s2q[(q*452+r)*4+p] = (r<450) ? Wpad[r*152+104+4q+p] : 0   (q<12, r<452)
__global__ void build_gsplit_kernel(const float* __restrict__ Wpad, float* __restrict__ s2q){
  int i = blockIdx.x*blockDim.x+threadIdx.x;
  if (i >= 12*452*4) return;
  int q = i/1808, rem = i-q*1808, r = rem/4, p = rem-r*4;
  s2q[i] = (r<450) ? Wpad[(size_t)r*152 + 104 + 4*q + p] : 0.f;
}

// ---- generic row-tiled projection; out stride ldo (zero-fill K..ldo)
__global__ __launch_bounds__(512) void rowproj_kernel(
    const float* __restrict__ Xrows,
    const int* __restrict__ gather, const void* __restrict__ Etab, const int* __restrict__ bfflag,
    const float* __restrict__ W, const float* __restrict__ bias,
    float* __restrict__ out, int rows, int K, int inner, int mode, int ldw, int offw, int ldo)
{
  __shared__ float xs[8][304];
  const int r0 = blockIdx.x*8;
  int nr = rows - r0; if (nr > 8) nr = 8;
  if (nr <= 0) return;
  const int isbf = gather ? *bfflag : 0;
  for (int e = threadIdx.x; e < nr*inner; e += blockDim.x){
    int r = e/inner, i = e - r*inner;
    float v;
    if (gather){
      size_t base = (size_t)gather[r0+r]*inner + i;
      v = isbf ? bf2f(((const unsigned short*)Etab)[base]) : ((const float*)Etab)[base];
    } else {
      v = Xrows[(size_t)(r0+r)*inner + i];
    }
    xs[r][i] = v;
  }
  __syncthreads();
  for (int k = threadIdx.x; k < ldo; k += blockDim.x){
    if (k < K){
      float b0 = bias ? bias[k] : 0.f;
      float acc[8];
      #pragma unroll
      for (int r=0;r<8;r++) acc[r] = b0;
      if (mode==0){
        for (int i=0;i<inner;i++){
          float wv = W[(size_t)i*ldw + k];
          #pragma unroll
          for (int r=0;r<8;r++) acc[r] += xs[r][i]*wv;
        }
      } else {
        const float* wr = W + (size_t)k*ldw + offw;
        for (int i=0;i<inner;i++){
          float wv = wr[i];
          #pragma unroll
          for (int r=0;r<8;r++) acc[r] += xs[r][i]*wv;
        }
      }
      for (int r=0;r<nr;r++) out[(size_t)(r0+r)*ldo + k] = acc[r];
    } else {
      for (int r=0;r<nr;r++) out[(size_t)(r0+r)*ldo + k] = 0.f;
    }
  }
}

// ---- 26-quad register macros ---------------------------------------------
#define R26(M) M(0) M(1) M(2) M(3) M(4) M(5) M(6) M(7) M(8) M(9) M(10) M(11) \
               M(12) M(13) M(14) M(15) M(16) M(17) M(18) M(19) M(20) M(21) \
               M(22) M(23) M(24) M(25)
#define DECW(i) float4 w##i;
#define LDW(i)  w##i = wrow4[i];
#define FMAW(i) { float4 hq = h4[i]; \
  acc0 = fmaf(hq.x, w##i.x, acc0); acc1 = fmaf(hq.y, w##i.y, acc1); \
  acc0 = fmaf(hq.z, w##i.z, acc0); acc1 = fmaf(hq.w, w##i.w, acc1); }

// ---- merged GRU encoder scan: blocks 0..31 context (S=400), 32..63 query (S=30)
__global__ __launch_bounds__(512) void gru_scan_kernel(
    const float* __restrict__ gi0, const float* __restrict__ Wp0,
    const float* __restrict__ s2q0, const float* __restrict__ bh0,
    float* __restrict__ H0, int S0,
    const float* __restrict__ gi1, const float* __restrict__ Wp1,
    const float* __restrict__ s2q1, const float* __restrict__ bh1,
    float* __restrict__ H1, int S1)
{
  const int blk = blockIdx.x;
  const float* gi; const float* Wpad; const float* s2qG; const float* bh; float* Hs; int S;
  if (blk < 32){ gi = gi0 + (size_t)blk*S0*450;  Wpad = Wp0; s2qG = s2q0; bh = bh0;
                 Hs = H0 + (size_t)blk*S0*150;   S = S0; }
  else         { int bb = blk-32;
                 gi = gi1 + (size_t)bb*S1*450;   Wpad = Wp1; s2qG = s2q1; bh = bh1;
                 Hs = H1 + (size_t)bb*S1*150;    S = S1; }
  __shared__ float4 s2W[12*452];              // transposed [q][r], 86,784 B
  __shared__ __align__(16) float h[152];
  __shared__ float gh[452];
  const int tid = threadIdx.x;

  R26(DECW)
  float br = 0.f;
  {
    const float4* wrow4 = (const float4*)(Wpad + (size_t)((tid<450)?tid:0)*152);
    R26(LDW)
    if (tid<450) br = bh[tid];
  }
  for (int e=tid; e<12*452; e+=512) s2W[e] = ((const float4*)s2qG)[e];
  if (tid < 152) h[tid] = 0.f;
  __syncthreads();
  const float4* h4 = (const float4*)h;

  for (int t=0;t<S;t++){
    float g0=0.f,g1=0.f,g2=0.f;
    if (tid < 150){
      const float* gg = gi + (size_t)t*450;
      g0 = gg[tid]; g1 = gg[150+tid]; g2 = gg[300+tid];
    }
    if (tid < 450){
      float acc0=br, acc1=0.f;
      R26(FMAW)
      #pragma unroll
      for (int q=0;q<12;q++){
        float4 wq = s2W[q*452+tid]; float4 hq = h4[26+q];
        acc0 = fmaf(hq.x, wq.x, acc0); acc1 = fmaf(hq.y, wq.y, acc1);
        acc0 = fmaf(hq.z, wq.z, acc0); acc1 = fmaf(hq.w, wq.w, acc1);
      }
      gh[tid] = acc0+acc1;
    }
    __syncthreads();
    if (tid < 150){
      float r = sigm(g0 + gh[tid]);
      float z = sigm(g1 + gh[150+tid]);
      float n = tanh_f(g2 + r*gh[300+tid]);
      float hn = (1.f-z)*n + z*h[tid];
      h[tid] = hn;
      Hs[(size_t)t*150 + tid] = hn;
    }
    __syncthreads();
  }
}

__global__ void zero_hr0_kernel(float* __restrict__ Hr){
  int idx = blockIdx.x*blockDim.x + threadIdx.x;
  if (idx < NBATCH*300){
    int b = idx/300, k = idx - 300*b;
    Hr[(size_t)b*T1*300 + k] = 0.f;
  }
}

// ---- match scan: one block per (batch, dir); 512 threads; 5 barriers/step.
__global__ __launch_bounds__(512) void match_scan_kernel(
    const float* __restrict__ pWp,   // [B,T,152]
    const float* __restrict__ whq,   // [B,J,152]
    const float* __restrict__ giXf,  // [B,T,452]
    const float* __restrict__ giXr,
    const float* __restrict__ Pf,    // [B,J,452]
    const float* __restrict__ Pr,
    const float* __restrict__ WcatF, const float* __restrict__ WcatR, // [600][152]
    const float* __restrict__ s2qF,  const float* __restrict__ s2qR,  // [12][512] f4
    const float* __restrict__ extF,  const float* __restrict__ extR,  // [38][88] f4
    const float* __restrict__ m_bhh, const float* __restrict__ mr_bhh,
    const float* __restrict__ wvec,  // [150]
    float* __restrict__ Hr)          // [B,401,300]
{
  const int b   = blockIdx.x;
  const int dir = blockIdx.y;
  const float* giX  = dir ? giXr : giXf;
  const float* P    = dir ? Pr   : Pf;
  const float* Wcat = dir ? WcatR : WcatF;
  const float* s2qG = dir ? s2qR  : s2qF;
  const float* extG = dir ? extR  : extF;
  const float* bhh  = dir ? mr_bhh : m_bhh;

  __shared__ float4 s2W[6144];                 // 98,304
  __shared__ float4 extW[3344];                // 53,504
  __shared__ float extPart[480];               //  1,920  [5][96] (k-62 indexed)
  __shared__ __align__(16) float h[152];       //    608
  __shared__ float ghsRaw[512];                //  2,048
  __shared__ __align__(16) float gis[452];     //  1,808
  __shared__ __align__(16) float pwS[152];     //    608
  __shared__ __align__(16) float wlS[152];     //    608
  __shared__ float sc[32], attw[32];           //    256  -> 159,664 B

  const int tid  = threadIdx.x;
  const int lane = tid & 63;
  const int wv   = tid >> 6;
  const int er   = (tid < 440) ? (tid % 88) : 0;   // ext row index
  const int kg   = (tid < 440) ? (tid / 88) : 0;   // ext K-group

  R26(DECW)
  float br;
  {
    const float4* wrow4 = (const float4*)(Wcat + (size_t)tid*152);
    R26(LDW)
    br = (tid < 450) ? bhh[tid] : 0.f;
  }
  for (int e=tid; e<6144; e+=512) s2W[e]  = ((const float4*)s2qG)[e];
  for (int e=tid; e<3344; e+=512) extW[e] = ((const float4*)extG)[e];
  if (tid < 152){
    h[tid] = 0.f;
    wlS[tid] = (tid<150) ? wvec[tid] : 0.f;
  }
  __syncthreads();
  const float4* h4 = (const float4*)h;

  for (int t=0;t<TLEN;t++){
    const int tt = dir ? (TLEN-1-t) : t;

    // ---- prefetch (issued before phase A; consumed after barriers) ----
    float gv = 0.f;
    if (tid < 452) gv = giX[((size_t)b*TLEN + tt)*452 + tid];   // HBM-ish
    float4 pwv;
    if (tid >= 440 && tid < 478)
      pwv = ((const float4*)(pWp + ((size_t)b*TLEN + tt)*152))[tid-440];

    // A: row dots for rows 0..511 (26 reg quads + 12 LDS quads)
    {
      float acc0=br, acc1=0.f;
      R26(FMAW)
      #pragma unroll
      for (int q=0;q<12;q++){
        float4 wq = s2W[q*512+tid]; float4 hq = h4[26+q];
        acc0 = fmaf(hq.x, wq.x, acc0); acc1 = fmaf(hq.y, wq.y, acc1);
        acc0 = fmaf(hq.z, wq.z, acc0); acc1 = fmaf(hq.w, wq.w, acc1);
      }
      ghsRaw[tid] = acc0+acc1;
    }
    // A-ext: Wcat rows 512..599 (Wr outputs k=62..149), 5 K-groups x 88 rows
    if (tid < 440){
      float e0=0.f, e1=0.f;
      #pragma unroll
      for (int j=0;j<8;j++){
        int q = kg*8+j;
        if (q < 38){
          float4 wq = extW[q*88+er]; float4 hq = h4[q];
          e0 = fmaf(hq.x,wq.x,e0); e1 = fmaf(hq.y,wq.y,e1);
          e0 = fmaf(hq.z,wq.z,e0); e1 = fmaf(hq.w,wq.w,e1);
        }
      }
      extPart[kg*96+er] = e0+e1;
    } else if (tid < 478){
      ((float4*)pwS)[tid-440] = pwv;
    }
    __syncthreads();                       // b1

    // B: scores with INLINE base (base = pw + h@Wr), lanes<38, j = wv+8*jj
    {
      float4 b4; b4.x=b4.y=b4.z=b4.w=0.f;
      const bool bl = (lane < 38);
      if (bl){
        float4 pw4 = ((const float4*)pwS)[lane];
        int k0 = 4*lane;
        float wr[4];
        #pragma unroll
        for (int c=0;c<4;c++){
          int k = k0+c;
          int e = (k >= 62) ? (k-62) : 0;
          float ext5 = extPart[e] + extPart[96+e] + extPart[192+e]
                     + extPart[288+e] + extPart[384+e];
          wr[c] = (k < 62) ? ghsRaw[450+k] : ext5;
        }
        b4.x = pw4.x + wr[0]; b4.y = pw4.y + wr[1];
        b4.z = pw4.z + wr[2]; b4.w = pw4.w + wr[3];
      }
      #pragma unroll
      for (int jj=0;jj<4;jj++){
        int j = wv + 8*jj;
        float a = 0.f;
        if (j < JQ && bl){
          float4 q4 = ((const float4*)(whq + ((size_t)b*JQ + j)*152))[lane];
          float4 w4 = ((const float4*)wlS)[lane];
          a = w4.x*tanh_f(q4.x+b4.x);
          a = fmaf(w4.y, tanh_f(q4.y+b4.y), a);
          a = fmaf(w4.z, tanh_f(q4.z+b4.z), a);
          a = fmaf(w4.w, tanh_f(q4.w+b4.w), a);
        }
        #pragma unroll
        for (int off=32; off; off>>=1) a += __shfl_down(a, off);
        if (j < JQ && lane==0) sc[j] = a;
      }
    }
    __syncthreads();                       // b2

    // C: softmax over J=30 (wave 0)
    if (tid < 64){
      float v = (tid < JQ) ? sc[tid] : -1e30f;
      float m = v;
      #pragma unroll
      for (int off=32; off; off>>=1) m = fmaxf(m, __shfl_down(m, off));
      m = __shfl(m, 0);
      float e = (tid < JQ) ? __expf(v-m) : 0.f;
      float su = e;
      #pragma unroll
      for (int off=32; off; off>>=1) su += __shfl_down(su, off);
      su = __shfl(su, 0);
      if (tid < JQ) attw[tid] = e/su;
    }
    __syncthreads();                       // b3

    // D: gis[k] = giX[k](prefetched) + sum_j attw[j]*P[j,k]; coalesced dwords
    if (tid < 452){
      float acc = gv;
      const float* Pb = P + (size_t)b*JQ*452 + tid;
      #pragma unroll 6
      for (int j=0;j<JQ;j++)
        acc = fmaf(attw[j], Pb[(size_t)j*452], acc);
      gis[tid] = acc;
    }
    __syncthreads();                       // b4

    // E: GRU combine, write Hr
    if (tid < 150){
      float r = sigm(gis[tid] + ghsRaw[tid]);
      float z = sigm(gis[150+tid] + ghsRaw[150+tid]);
      float n = tanh_f(gis[300+tid] + r*ghsRaw[300+tid]);
      float hn = (1.f-z)*n + z*h[tid];
      h[tid] = hn;
      Hr[((size_t)b*T1 + (t+1))*300 + dir*150 + tid] = hn;
    }
    __syncthreads();                       // b5
  }
}

// ---- pointer decoder
__global__ __launch_bounds__(512,2) void ptr_scan_kernel(
    const float* __restrict__ enc, const float* __restrict__ Hr,
    const float* __restrict__ W2, const float* __restrict__ pv,
    const float* __restrict__ dWih, const float* __restrict__ dWhh,
    const float* __restrict__ dbih, const float* __restrict__ dbhh,
    void* __restrict__ outv, const int* __restrict__ flag)
{
  const int b = blockIdx.x;
  const int tid = threadIdx.x;
  const int isbf = *flag;
  __shared__ float h[300], hW2[300], sl[T1], al[T1], c[300];
  __shared__ float gis[900], ghs[900];
  __shared__ float vl[300];
  __shared__ float red[8];
  if (tid < 300){ h[tid] = 0.f; vl[tid] = pv[tid]; }
  __syncthreads();
  for (int l=0;l<2;l++){
    if (tid < 300){
      float a0=0.f,a1=0.f;
      for (int i=0;i<300;i+=2){
        a0 += h[i]  *W2[(size_t)i*300+tid];
        a1 += h[i+1]*W2[(size_t)(i+1)*300+tid];
      }
      hW2[tid] = a0+a1;
    }
    __syncthreads();
    {
      const int wv = tid>>6, lane = tid&63;
      for (int t=wv; t<T1; t+=8){
        const float* er = enc + ((size_t)b*T1 + t)*300;
        float acc = 0.f;
        for (int k=lane; k<300; k+=64) acc += vl[k]*tanh_f(er[k] + hW2[k]);
        #pragma unroll
        for (int off=32; off; off>>=1) acc += __shfl_down(acc, off);
        if (lane==0) sl[t] = acc;
      }
    }
    __syncthreads();
    {
      float v = (tid < T1) ? sl[tid] : -1e30f;
      float m = v;
      #pragma unroll
      for (int off=32; off; off>>=1) m = fmaxf(m, __shfl_down(m, off));
      if ((tid&63)==0) red[tid>>6] = m;
      __syncthreads();
      float bm = fmaxf(fmaxf(fmaxf(red[0],red[1]),fmaxf(red[2],red[3])),
                       fmaxf(fmaxf(red[4],red[5]),fmaxf(red[6],red[7])));
      float e = (tid < T1) ? __expf(v-bm) : 0.f;
      float su = e;
      #pragma unroll
      for (int off=32; off; off>>=1) su += __shfl_down(su, off);
      __syncthreads();
      if ((tid&63)==0) red[tid>>6] = su;
      __syncthreads();
      float bs = red[0]+red[1]+red[2]+red[3]+red[4]+red[5]+red[6]+red[7];
      if (tid < T1){
        float a = e/bs;
        al[tid] = a;
        size_t oi = ((size_t)b*2 + l)*T1 + tid;
        if (isbf) ((__hip_bfloat16*)outv)[oi] = __float2bfloat16(a);
        else      ((float*)outv)[oi] = a;
      }
    }
    __syncthreads();
    if (tid < 300){
      float acc = 0.f;
      for (int t=0;t<T1;t++) acc += al[t]*Hr[((size_t)b*T1 + t)*300 + tid];
      c[tid] = acc;
    }
    __syncthreads();
    for (int k=tid; k<900; k+=blockDim.x){
      const float* wi = dWih + (size_t)k*300;
      const float* wh = dWhh + (size_t)k*300;
      float a0 = dbih[k], a1 = dbhh[k];
      for (int i=0;i<300;i++){ a0 += c[i]*wi[i]; a1 += h[i]*wh[i]; }
      gis[k] = a0; ghs[k] = a1;
    }
    __syncthreads();
    if (tid < 300){
      float r = sigm(gis[tid] + ghs[tid]);
      float z = sigm(gis[300+tid] + ghs[300+tid]);
      float n = tanh_f(gis[600+tid] + r*ghs[600+tid]);
      h[tid] = (1.f-z)*n + z*h[tid];
    }
    __syncthreads();
  }
}

} // namespace

extern "C" void kernel_launch(void* const* d_in, const int* in_sizes, int n_in,
                              void* d_out, int out_size, void* d_ws, size_t ws_size,
                              hipStream_t stream)
{
  (void)in_sizes; (void)n_in; (void)out_size; (void)ws_size;
  float* ws = (float*)d_ws;
  int* flag = (int*)d_ws;

  static const int wsz[NW] = {
    67500,67500,450,450,
    67500,67500,450,450,
    22500,22500,22500,150,150,1,
    135000,67500,450,450,
    135000,67500,450,450,
    90000,90000,300,
    270000,270000,900,900
  };
  WDesc desc;
  int cum = 0;
  for (int j=0;j<NW;j++){ desc.src[j] = d_in[3+j]; desc.off[j] = cum; cum += wsz[j]; }
  desc.off[NW] = cum;

  float* WB = ws + 16;
  const float* P_ctx_Wih = WB + desc.off[0];
  const float* P_ctx_Whh = WB + desc.off[1];
  const float* P_ctx_bih = WB + desc.off[2];
  const float* P_ctx_bhh = WB + desc.off[3];
  const float* P_q_Wih   = WB + desc.off[4];
  const float* P_q_Whh   = WB + desc.off[5];
  const float* P_q_bih   = WB + desc.off[6];
  const float* P_q_bhh   = WB + desc.off[7];
  const float* P_Wq      = WB + desc.off[8];
  const float* P_Wp      = WB + desc.off[9];
  const float* P_Wr      = WB + desc.off[10];
  const float* P_w       = WB + desc.off[11];
  const float* P_gb      = WB + desc.off[12];
  const float* P_m_Wih   = WB + desc.off[14];
  const float* P_m_Whh   = WB + desc.off[15];
  const float* P_m_bih   = WB + desc.off[16];
  const float* P_m_bhh   = WB + desc.off[17];
  const float* P_mr_Wih  = WB + desc.off[18];
  const float* P_mr_Whh  = WB + desc.off[19];
  const float* P_mr_bih  = WB + desc.off[20];
  const float* P_mr_bhh  = WB + desc.off[21];
  const float* P_W1      = WB + desc.off[22];
  const float* P_W2      = WB + desc.off[23];
  const float* P_pv      = WB + desc.off[24];
  const float* P_dWih    = WB + desc.off[25];
  const float* P_dWhh    = WB + desc.off[26];
  const float* P_dbih    = WB + desc.off[27];
  const float* P_dbhh    = WB + desc.off[28];

  size_t p = 16 + 1468512;
  float* ctxWhhP = ws + p; p += 68400;    // [450][152]
  float* qWhhP   = ws + p; p += 68400;
  float* s2qCtx  = ws + p; p += 21696;    // [12][452] f4
  float* s2qQ    = ws + p; p += 21696;
  float* WcatF   = ws + p; p += 91200;    // [600][152]
  float* WcatR   = ws + p; p += 91200;
  float* s2qF    = ws + p; p += 24576;    // [12][512] f4
  float* s2qR    = ws + p; p += 24576;
  float* extFg   = ws + p; p += 13376;    // [38][88] f4
  float* extRg   = ws + p; p += 13376;

  float* ctx_gi = ws + p; p += 5760000;   // [B,T,450]; reused as enc later
  float* q_gi   = ws + p; p += 432000;    // [B,J,450]
  float* HpB    = ws + p; p += 1920000;   // [B,T,150]
  float* HqB    = ws + p; p += 144000;    // [B,J,150]
  float* whqB   = ws + p; p += 145920;    // [B,J,152]
  float* PfB    = ws + p; p += 433920;    // [B,J,452]
  float* PrB    = ws + p; p += 433920;
  float* pWpB   = ws + p; p += 1945600;   // [B,T,152]
  float* giXfB  = ws + p; p += 5785600;   // [B,T,452]
  float* giXrB  = ws + p; p += 5785600;
  float* HrB    = ws + p; p += 3849600;   // [B,401,300]
  float* encB   = ctx_gi;                 // [B,401,300]

  // 1) dtype sniff + weight conversion + restructured layouts
  sniff_kernel<<<1,256,0,stream>>>((const unsigned int*)d_in[2], flag);
  convert_weights_kernel<<<512,256,0,stream>>>(desc, WB, flag);
  padrows_kernel<<<(450*152+255)/256,256,0,stream>>>(P_ctx_Whh, ctxWhhP, 450,150,152);
  padrows_kernel<<<(450*152+255)/256,256,0,stream>>>(P_q_Whh,   qWhhP,   450,150,152);
  build_gsplit_kernel<<<(12*452*4+255)/256,256,0,stream>>>(ctxWhhP, s2qCtx);
  build_gsplit_kernel<<<(12*452*4+255)/256,256,0,stream>>>(qWhhP,   s2qQ);
  build_wcat_kernel<<<(600*152+255)/256,256,0,stream>>>(P_m_Whh,  P_Wr, WcatF);
  build_wcat_kernel<<<(600*152+255)/256,256,0,stream>>>(P_mr_Whh, P_Wr, WcatR);
  build_msplit_kernel<<<(24576+13376+255)/256,256,0,stream>>>(WcatF, s2qF, extFg);
  build_msplit_kernel<<<(24576+13376+255)/256,256,0,stream>>>(WcatR, s2qR, extRg);

  // 2) embedding + input projections for both encoders
  rowproj_kernel<<<1600,512,0,stream>>>(nullptr,(const int*)d_in[0], d_in[2], flag,
                                        P_ctx_Wih, P_ctx_bih, ctx_gi, 12800,450,150,1,150,0,450);
  rowproj_kernel<<<120,512,0,stream>>>(nullptr,(const int*)d_in[1], d_in[2], flag,
                                       P_q_Wih, P_q_bih, q_gi, 960,450,150,1,150,0,450);

  // 3) encoder scans
  gru_scan_kernel<<<64,512,0,stream>>>(ctx_gi, ctxWhhP, s2qCtx, P_ctx_bhh, HpB, 400,
                                       q_gi,   qWhhP,   s2qQ,   P_q_bhh,   HqB, 30);

  // 4) Hq/Hp-dependent precomputations (padded strides)
  rowproj_kernel<<<120,192,0,stream>>>(HqB,nullptr,nullptr,nullptr, P_Wq, nullptr,
                                       whqB, 960,150,150,0,150,0,152);
  rowproj_kernel<<<120,512,0,stream>>>(HqB,nullptr,nullptr,nullptr, P_m_Wih, nullptr,
                                       PfB, 960,450,150,1,300,150,452);
  rowproj_kernel<<<120,512,0,stream>>>(HqB,nullptr,nullptr,nullptr, P_mr_Wih, nullptr,
                                       PrB, 960,450,150,1,300,150,452);
  rowproj_kernel<<<1600,192,0,stream>>>(HpB,nullptr,nullptr,nullptr, P_Wp, P_gb,
                                        pWpB, 12800,150,150,0,150,0,152);
  rowproj_kernel<<<1600,512,0,stream>>>(HpB,nullptr,nullptr,nullptr, P_m_Wih, P_m_bih,
                                        giXfB, 12800,450,150,1,300,0,452);
  rowproj_kernel<<<1600,512,0,stream>>>(HpB,nullptr,nullptr,nullptr, P_mr_Wih, P_mr_bih,
                                        giXrB, 12800,450,150,1,300,0,452);

  // 5) match scans (fwd+bwd concurrent)
  zero_hr0_kernel<<<(NBATCH*300+511)/512,512,0,stream>>>(HrB);
  match_scan_kernel<<<dim3(NBATCH,2),512,0,stream>>>(pWpB, whqB, giXfB, giXrB,
                                                     PfB, PrB, WcatF, WcatR,
                                                     s2qF, s2qR, extFg, extRg,
                                                     P_m_bhh, P_mr_bhh, P_w, HrB);

  // 6) pointer decoder
  rowproj_kernel<<<1604,320,0,stream>>>(HrB,nullptr,nullptr,nullptr, P_W1, nullptr,
                                        encB, 12832,300,300,0,300,0,300);
  ptr_scan_kernel<<<32,512,0,stream>>>(encB, HrB, P_W2, P_pv,
                                       P_dWih, P_dWhh, P_dbih, P_dbhh, d_out, flag);
}

// Round 9
// 3526.997 us; speedup vs baseline: 2.4013x; 1.0237x over previous
//
#include <hip/hip_runtime.h>
#include <hip/hip_bf16.h>

// MatchLSTM boundary-pointer model on MI355X (gfx950).
// B=32 T=400 J=30 V=50000 D=150 H=150 L=2. Output [B,2,401].
//
// Round 9 = round 8 (3610us) + two fixes:
//  1) match phase-B inline base made conflict-free: wrP[5][152] indexed by k
//     (ext partials at [kg][62+er], rows 450-511 write [0][k<62]); phase B
//     reads 5 aligned float4s/lane. Round 8's lane-stride-4 dword reads had
//     blown SQ_LDS_BANK_CONFLICT 1.3M -> 8.27M.
//  2) rowproj16: all projections mode-0 (weights pre-transposed), 16-row
//     tiles, 4-i unroll with b128 x-broadcast reads -> LDS:FMA 1:4 and 2x
//     weight reuse (old kernel was scalar-stream / 1:1).

namespace {

constexpr int NBATCH = 32;
constexpr int TLEN   = 400;
constexpr int JQ     = 30;
constexpr int T1     = 401;

__device__ __forceinline__ float sigm(float x){ return 1.f/(1.f+__expf(-x)); }
__device__ __forceinline__ float tanh_f(float x){
  float e = __expf(-2.f*fabsf(x));
  float t = (1.f-e)/(1.f+e);
  return x < 0.f ? -t : t;
}
__device__ __forceinline__ float bf2f(unsigned short u){
  union { unsigned int i; float f; } c; c.i = ((unsigned int)u)<<16; return c.f;
}

#define NW 29
struct WDesc { const void* src[NW]; int off[NW+1]; };

__global__ void sniff_kernel(const unsigned int* __restrict__ bits, int* __restrict__ flag){
  __shared__ int cnt;
  if (threadIdx.x==0) cnt = 0;
  __syncthreads();
  int hit = 0;
  #pragma unroll
  for (int i=0;i<4;i++){
    unsigned int w = bits[threadIdx.x*4+i];
    unsigned int b = (w>>8)&0x7Fu;
    if (b==0u || (b>=0x38u && b<=0x3Fu)) hit++;
  }
  atomicAdd(&cnt, hit);
  __syncthreads();
  if (threadIdx.x==0) *flag = (cnt > 768) ? 1 : 0;
}

__global__ void convert_weights_kernel(WDesc d, float* __restrict__ out, const int* __restrict__ flag){
  const int isbf = *flag;
  const int total = d.off[NW];
  for (int e = blockIdx.x*blockDim.x+threadIdx.x; e < total; e += gridDim.x*blockDim.x){
    int j = 0;
    while (e >= d.off[j+1]) j++;
    int i = e - d.off[j];
    out[e] = isbf ? bf2f(((const unsigned short*)d.src[j])[i])
                  : ((const float*)d.src[j])[i];
  }
}

__global__ void padrows_kernel(const float* __restrict__ src, float* __restrict__ dst,
                               int rows, int cols, int ldd){
  int i = blockIdx.x*blockDim.x+threadIdx.x;
  if (i >= rows*ldd) return;
  int r = i/ldd, c = i-r*ldd;
  dst[i] = (c<cols) ? src[(size_t)r*cols+c] : 0.f;
}

// dst[i*R + k] = src[k*lds_ + offs + i]   (i<C inner, k<R)
__global__ void transpose_kernel(const float* __restrict__ src, float* __restrict__ dst,
                                 int R, int C, int lds_, int offs){
  int idx = blockIdx.x*blockDim.x+threadIdx.x;
  if (idx >= R*C) return;
  int i = idx / R, k = idx - i*R;
  dst[(size_t)i*R + k] = src[(size_t)k*lds_ + offs + i];
}

// Wcat[600][152]: rows<450 = Whh; rows>=450: Wcat[450+k][i] = Wr[i][k]
__global__ void build_wcat_kernel(const float* __restrict__ Whh, const float* __restrict__ Wr,
                                  float* __restrict__ Wcat){
  int i = blockIdx.x*blockDim.x+threadIdx.x;
  if (i >= 600*152) return;
  int r = i/152, c = i-r*152;
  float v = 0.f;
  if (c < 150){
    if (r < 450) v = Whh[(size_t)r*150+c];
    else         v = Wr[(size_t)c*150 + (r-450)];
  }
  Wcat[i] = v;
}

// s2q[(q*512+r)*4+p] = Wcat[r*152+104+4q+p]  (q<12, r<512)
// ext[(q*88+i)*4+p]  = Wcat[(512+i)*152+4q+p] (q<38, i<88)
__global__ void build_msplit_kernel(const float* __restrict__ Wcat,
                                    float* __restrict__ s2q, float* __restrict__ ext){
  int i = blockIdx.x*blockDim.x+threadIdx.x;
  if (i < 24576){
    int q = i/2048, rem = i-q*2048, r = rem/4, p = rem-r*4;
    s2q[i] = Wcat[(size_t)r*152 + 104 + 4*q + p];
  } else if (i < 24576+13376){
    int k = i-24576;
    int q = k/352, rem = k-q*352, ii = rem/4, p = rem-ii*4;
    ext[k] = Wcat[(size_t)(512+ii)*152 + 4*q + p];
  }
}

// s2q[(q*452+r)*4+p] = (r<450) ? Wpad[r*152+104+4q+p] : 0   (q<12, r<452)
__global__ void build_gsplit_kernel(const float* __restrict__ Wpad, float* __restrict__ s2q){
  int i = blockIdx.x*blockDim.x+threadIdx.x;
  if (i >= 12*452*4) return;
  int q = i/1808, rem = i-q*1808, r = rem/4, p = rem-r*4;
  s2q[i] = (r<450) ? Wpad[(size_t)r*152 + 104 + 4*q + p] : 0.f;
}

// ---- 16-row mode-0 projection: out[r,k] = bias[k] + sum_i x[r,i]*W[i*ldw+k]
__global__ __launch_bounds__(512) void rowproj16_kernel(
    const float* __restrict__ Xrows,
    const int* __restrict__ gather, const void* __restrict__ Etab, const int* __restrict__ bfflag,
    const float* __restrict__ W, const float* __restrict__ bias,
    float* __restrict__ out, int rows, int K, int inner, int ldw, int ldo)
{
  __shared__ __align__(16) float xs[16][304];
  const int r0 = blockIdx.x*16;
  int nr = rows - r0; if (nr > 16) nr = 16;
  if (nr <= 0) return;
  const int isbf = gather ? *bfflag : 0;
  for (int e = threadIdx.x; e < nr*inner; e += 512){
    int r = e/inner, i = e - r*inner;
    float v;
    if (gather){
      size_t base = (size_t)gather[r0+r]*inner + i;
      v = isbf ? bf2f(((const unsigned short*)Etab)[base]) : ((const float*)Etab)[base];
    } else {
      v = Xrows[(size_t)(r0+r)*inner + i];
    }
    xs[r][i] = v;
  }
  __syncthreads();
  for (int k = threadIdx.x; k < K; k += 512){
    float b0 = bias ? bias[k] : 0.f;
    float acc[16];
    #pragma unroll
    for (int r=0;r<16;r++) acc[r] = b0;
    int i = 0;
    for (; i+4 <= inner; i += 4){
      float w0 = W[(size_t)i*ldw + k];
      float w1 = W[(size_t)(i+1)*ldw + k];
      float w2 = W[(size_t)(i+2)*ldw + k];
      float w3 = W[(size_t)(i+3)*ldw + k];
      #pragma unroll
      for (int r=0;r<16;r++){
        float4 xv = *(const float4*)&xs[r][i];
        acc[r] = fmaf(xv.x, w0, acc[r]);
        acc[r] = fmaf(xv.y, w1, acc[r]);
        acc[r] = fmaf(xv.z, w2, acc[r]);
        acc[r] = fmaf(xv.w, w3, acc[r]);
      }
    }
    for (; i < inner; i++){
      float wv = W[(size_t)i*ldw + k];
      #pragma unroll
      for (int r=0;r<16;r++) acc[r] = fmaf(xs[r][i], wv, acc[r]);
    }
    for (int r=0;r<nr;r++) out[(size_t)(r0+r)*ldo + k] = acc[r];
  }
  for (int k = K + threadIdx.x; k < ldo; k += 512)
    for (int r=0;r<nr;r++) out[(size_t)(r0+r)*ldo + k] = 0.f;
}

// ---- 26-quad register macros ---------------------------------------------
#define R26(M) M(0) M(1) M(2) M(3) M(4) M(5) M(6) M(7) M(8) M(9) M(10) M(11) \
               M(12) M(13) M(14) M(15) M(16) M(17) M(18) M(19) M(20) M(21) \
               M(22) M(23) M(24) M(25)
#define DECW(i) float4 w##i;
#define LDW(i)  w##i = wrow4[i];
#define FMAW(i) { float4 hq = h4[i]; \
  acc0 = fmaf(hq.x, w##i.x, acc0); acc1 = fmaf(hq.y, w##i.y, acc1); \
  acc0 = fmaf(hq.z, w##i.z, acc0); acc1 = fmaf(hq.w, w##i.w, acc1); }

// ---- merged GRU encoder scan: blocks 0..31 context (S=400), 32..63 query (S=30)
__global__ __launch_bounds__(512) void gru_scan_kernel(
    const float* __restrict__ gi0, const float* __restrict__ Wp0,
    const float* __restrict__ s2q0, const float* __restrict__ bh0,
    float* __restrict__ H0, int S0,
    const float* __restrict__ gi1, const float* __restrict__ Wp1,
    const float* __restrict__ s2q1, const float* __restrict__ bh1,
    float* __restrict__ H1, int S1)
{
  const int blk = blockIdx.x;
  const float* gi; const float* Wpad; const float* s2qG; const float* bh; float* Hs; int S;
  if (blk < 32){ gi = gi0 + (size_t)blk*S0*450;  Wpad = Wp0; s2qG = s2q0; bh = bh0;
                 Hs = H0 + (size_t)blk*S0*150;   S = S0; }
  else         { int bb = blk-32;
                 gi = gi1 + (size_t)bb*S1*450;   Wpad = Wp1; s2qG = s2q1; bh = bh1;
                 Hs = H1 + (size_t)bb*S1*150;    S = S1; }
  __shared__ float4 s2W[12*452];              // transposed [q][r], 86,784 B
  __shared__ __align__(16) float h[152];
  __shared__ float gh[452];
  const int tid = threadIdx.x;

  R26(DECW)
  float br = 0.f;
  {
    const float4* wrow4 = (const float4*)(Wpad + (size_t)((tid<450)?tid:0)*152);
    R26(LDW)
    if (tid<450) br = bh[tid];
  }
  for (int e=tid; e<12*452; e+=512) s2W[e] = ((const float4*)s2qG)[e];
  if (tid < 152) h[tid] = 0.f;
  __syncthreads();
  const float4* h4 = (const float4*)h;

  for (int t=0;t<S;t++){
    float g0=0.f,g1=0.f,g2=0.f;
    if (tid < 150){
      const float* gg = gi + (size_t)t*450;
      g0 = gg[tid]; g1 = gg[150+tid]; g2 = gg[300+tid];
    }
    if (tid < 450){
      float acc0=br, acc1=0.f;
      R26(FMAW)
      #pragma unroll
      for (int q=0;q<12;q++){
        float4 wq = s2W[q*452+tid]; float4 hq = h4[26+q];
        acc0 = fmaf(hq.x, wq.x, acc0); acc1 = fmaf(hq.y, wq.y, acc1);
        acc0 = fmaf(hq.z, wq.z, acc0); acc1 = fmaf(hq.w, wq.w, acc1);
      }
      gh[tid] = acc0+acc1;
    }
    __syncthreads();
    if (tid < 150){
      float r = sigm(g0 + gh[tid]);
      float z = sigm(g1 + gh[150+tid]);
      float n = tanh_f(g2 + r*gh[300+tid]);
      float hn = (1.f-z)*n + z*h[tid];
      h[tid] = hn;
      Hs[(size_t)t*150 + tid] = hn;
    }
    __syncthreads();
  }
}

__global__ void zero_hr0_kernel(float* __restrict__ Hr){
  int idx = blockIdx.x*blockDim.x + threadIdx.x;
  if (idx < NBATCH*300){
    int b = idx/300, k = idx - 300*b;
    Hr[(size_t)b*T1*300 + k] = 0.f;
  }
}

// ---- match scan: one block per (batch, dir); 512 threads; 5 barriers/step.
__global__ __launch_bounds__(512) void match_scan_kernel(
    const float* __restrict__ pWp,   // [B,T,152]
    const float* __restrict__ whq,   // [B,J,152]
    const float* __restrict__ giXf,  // [B,T,452]
    const float* __restrict__ giXr,
    const float* __restrict__ Pf,    // [B,J,452]
    const float* __restrict__ Pr,
    const float* __restrict__ WcatF, const float* __restrict__ WcatR, // [600][152]
    const float* __restrict__ s2qF,  const float* __restrict__ s2qR,  // [12][512] f4
    const float* __restrict__ extF,  const float* __restrict__ extR,  // [38][88] f4
    const float* __restrict__ m_bhh, const float* __restrict__ mr_bhh,
    const float* __restrict__ wvec,  // [150]
    float* __restrict__ Hr)          // [B,401,300]
{
  const int b   = blockIdx.x;
  const int dir = blockIdx.y;
  const float* giX  = dir ? giXr : giXf;
  const float* P    = dir ? Pr   : Pf;
  const float* Wcat = dir ? WcatR : WcatF;
  const float* s2qG = dir ? s2qR  : s2qF;
  const float* extG = dir ? extR  : extF;
  const float* bhh  = dir ? mr_bhh : m_bhh;

  __shared__ float4 s2W[6144];                 // 98,304
  __shared__ float4 extW[3344];                // 53,504
  __shared__ __align__(16) float wrP[760];     //  3,040  [5][152], k-indexed
  __shared__ __align__(16) float h[152];       //    608
  __shared__ float ghsRaw[512];                //  2,048
  __shared__ __align__(16) float gis[452];     //  1,808
  __shared__ __align__(16) float pwS[152];     //    608
  __shared__ __align__(16) float wlS[152];     //    608
  __shared__ float sc[32], attw[32];           //    256  -> 160,784 B

  const int tid  = threadIdx.x;
  const int lane = tid & 63;
  const int wv   = tid >> 6;
  const int er   = (tid < 440) ? (tid % 88) : 0;   // ext row index (k=62+er)
  const int kg   = (tid < 440) ? (tid / 88) : 0;   // ext K-group / wrP segment

  R26(DECW)
  float br;
  {
    const float4* wrow4 = (const float4*)(Wcat + (size_t)tid*152);
    R26(LDW)
    br = (tid < 450) ? bhh[tid] : 0.f;
  }
  for (int e=tid; e<6144; e+=512) s2W[e]  = ((const float4*)s2qG)[e];
  for (int e=tid; e<3344; e+=512) extW[e] = ((const float4*)extG)[e];
  if (tid < 760) wrP[tid] = 0.f;               // segs1-4 k<62 + pads stay 0
  if (tid < 152){
    h[tid] = 0.f;
    wlS[tid] = (tid<150) ? wvec[tid] : 0.f;
  }
  __syncthreads();
  const float4* h4 = (const float4*)h;
  const float4* wrP4 = (const float4*)wrP;

  for (int t=0;t<TLEN;t++){
    const int tt = dir ? (TLEN-1-t) : t;

    // ---- prefetch (issued before phase A; consumed after barriers) ----
    float gv = 0.f;
    if (tid < 452) gv = giX[((size_t)b*TLEN + tt)*452 + tid];
    float4 pwv;
    if (tid >= 440 && tid < 478)
      pwv = ((const float4*)(pWp + ((size_t)b*TLEN + tt)*152))[tid-440];

    // A: row dots for rows 0..511 (26 reg quads + 12 LDS quads)
    {
      float acc0=br, acc1=0.f;
      R26(FMAW)
      #pragma unroll
      for (int q=0;q<12;q++){
        float4 wq = s2W[q*512+tid]; float4 hq = h4[26+q];
        acc0 = fmaf(hq.x, wq.x, acc0); acc1 = fmaf(hq.y, wq.y, acc1);
        acc0 = fmaf(hq.z, wq.z, acc0); acc1 = fmaf(hq.w, wq.w, acc1);
      }
      float v = acc0+acc1;
      ghsRaw[tid] = v;
      if (tid >= 450) wrP[tid-450] = v;        // seg0, k=0..61
    }
    // A-ext: Wcat rows 512..599 (Wr outputs k=62..149), 5 K-groups x 88 rows
    if (tid < 440){
      float e0=0.f, e1=0.f;
      #pragma unroll
      for (int j=0;j<8;j++){
        int q = kg*8+j;
        if (q < 38){
          float4 wq = extW[q*88+er]; float4 hq = h4[q];
          e0 = fmaf(hq.x,wq.x,e0); e1 = fmaf(hq.y,wq.y,e1);
          e0 = fmaf(hq.z,wq.z,e0); e1 = fmaf(hq.w,wq.w,e1);
        }
      }
      wrP[kg*152 + 62 + er] = e0+e1;
    }
    if (tid >= 440 && tid < 478) ((float4*)pwS)[tid-440] = pwv;
    __syncthreads();                       // b1

    // B: scores with inline base = pw + sum_seg wrP (aligned f4 reads)
    {
      float4 b4; b4.x=b4.y=b4.z=b4.w=0.f;
      const bool bl = (lane < 38);
      if (bl){
        float4 pw4 = ((const float4*)pwS)[lane];
        float4 s0 = wrP4[lane],        s1 = wrP4[38+lane];
        float4 s2 = wrP4[76+lane],     s3 = wrP4[114+lane];
        float4 s4 = wrP4[152+lane];
        b4.x = pw4.x + s0.x+s1.x+s2.x+s3.x+s4.x;
        b4.y = pw4.y + s0.y+s1.y+s2.y+s3.y+s4.y;
        b4.z = pw4.z + s0.z+s1.z+s2.z+s3.z+s4.z;
        b4.w = pw4.w + s0.w+s1.w+s2.w+s3.w+s4.w;
      }
      #pragma unroll
      for (int jj=0;jj<4;jj++){
        int j = wv + 8*jj;
        float a = 0.f;
        if (j < JQ && bl){
          float4 q4 = ((const float4*)(whq + ((size_t)b*JQ + j)*152))[lane];
          float4 w4 = ((const float4*)wlS)[lane];
          a = w4.x*tanh_f(q4.x+b4.x);
          a = fmaf(w4.y, tanh_f(q4.y+b4.y), a);
          a = fmaf(w4.z, tanh_f(q4.z+b4.z), a);
          a = fmaf(w4.w, tanh_f(q4.w+b4.w), a);
        }
        #pragma unroll
        for (int off=32; off; off>>=1) a += __shfl_down(a, off);
        if (j < JQ && lane==0) sc[j] = a;
      }
    }
    __syncthreads();                       // b2

    // C: softmax over J=30 (wave 0)
    if (tid < 64){
      float v = (tid < JQ) ? sc[tid] : -1e30f;
      float m = v;
      #pragma unroll
      for (int off=32; off; off>>=1) m = fmaxf(m, __shfl_down(m, off));
      m = __shfl(m, 0);
      float e = (tid < JQ) ? __expf(v-m) : 0.f;
      float su = e;
      #pragma unroll
      for (int off=32; off; off>>=1) su += __shfl_down(su, off);
      su = __shfl(su, 0);
      if (tid < JQ) attw[tid] = e/su;
    }
    __syncthreads();                       // b3

    // D: gis[k] = giX[k](prefetched) + sum_j attw[j]*P[j,k]; coalesced dwords
    if (tid < 452){
      float acc = gv;
      const float* Pb = P + (size_t)b*JQ*452 + tid;
      #pragma unroll 6
      for (int j=0;j<JQ;j++)
        acc = fmaf(attw[j], Pb[(size_t)j*452], acc);
      gis[tid] = acc;
    }
    __syncthreads();                       // b4

    // E: GRU combine, write Hr
    if (tid < 150){
      float r = sigm(gis[tid] + ghsRaw[tid]);
      float z = sigm(gis[150+tid] + ghsRaw[150+tid]);
      float n = tanh_f(gis[300+tid] + r*ghsRaw[300+tid]);
      float hn = (1.f-z)*n + z*h[tid];
      h[tid] = hn;
      Hr[((size_t)b*T1 + (t+1))*300 + dir*150 + tid] = hn;
    }
    __syncthreads();                       // b5
  }
}

// ---- pointer decoder
__global__ __launch_bounds__(512,2) void ptr_scan_kernel(
    const float* __restrict__ enc, const float* __restrict__ Hr,
    const float* __restrict__ W2, const float* __restrict__ pv,
    const float* __restrict__ dWih, const float* __restrict__ dWhh,
    const float* __restrict__ dbih, const float* __restrict__ dbhh,
    void* __restrict__ outv, const int* __restrict__ flag)
{
  const int b = blockIdx.x;
  const int tid = threadIdx.x;
  const int isbf = *flag;
  __shared__ float h[300], hW2[300], sl[T1], al[T1], c[300];
  __shared__ float gis[900], ghs[900];
  __shared__ float vl[300];
  __shared__ float red[8];
  if (tid < 300){ h[tid] = 0.f; vl[tid] = pv[tid]; }
  __syncthreads();
  for (int l=0;l<2;l++){
    if (tid < 300){
      float a0=0.f,a1=0.f;
      for (int i=0;i<300;i+=2){
        a0 += h[i]  *W2[(size_t)i*300+tid];
        a1 += h[i+1]*W2[(size_t)(i+1)*300+tid];
      }
      hW2[tid] = a0+a1;
    }
    __syncthreads();
    {
      const int wv = tid>>6, lane = tid&63;
      for (int t=wv; t<T1; t+=8){
        const float* er = enc + ((size_t)b*T1 + t)*300;
        float acc = 0.f;
        for (int k=lane; k<300; k+=64) acc += vl[k]*tanh_f(er[k] + hW2[k]);
        #pragma unroll
        for (int off=32; off; off>>=1) acc += __shfl_down(acc, off);
        if (lane==0) sl[t] = acc;
      }
    }
    __syncthreads();
    {
      float v = (tid < T1) ? sl[tid] : -1e30f;
      float m = v;
      #pragma unroll
      for (int off=32; off; off>>=1) m = fmaxf(m, __shfl_down(m, off));
      if ((tid&63)==0) red[tid>>6] = m;
      __syncthreads();
      float bm = fmaxf(fmaxf(fmaxf(red[0],red[1]),fmaxf(red[2],red[3])),
                       fmaxf(fmaxf(red[4],red[5]),fmaxf(red[6],red[7])));
      float e = (tid < T1) ? __expf(v-bm) : 0.f;
      float su = e;
      #pragma unroll
      for (int off=32; off; off>>=1) su += __shfl_down(su, off);
      __syncthreads();
      if ((tid&63)==0) red[tid>>6] = su;
      __syncthreads();
      float bs = red[0]+red[1]+red[2]+red[3]+red[4]+red[5]+red[6]+red[7];
      if (tid < T1){
        float a = e/bs;
        al[tid] = a;
        size_t oi = ((size_t)b*2 + l)*T1 + tid;
        if (isbf) ((__hip_bfloat16*)outv)[oi] = __float2bfloat16(a);
        else      ((float*)outv)[oi] = a;
      }
    }
    __syncthreads();
    if (tid < 300){
      float acc = 0.f;
      for (int t=0;t<T1;t++) acc += al[t]*Hr[((size_t)b*T1 + t)*300 + tid];
      c[tid] = acc;
    }
    __syncthreads();
    for (int k=tid; k<900; k+=blockDim.x){
      const float* wi = dWih + (size_t)k*300;
      const float* wh = dWhh + (size_t)k*300;
      float a0 = dbih[k], a1 = dbhh[k];
      for (int i=0;i<300;i++){ a0 += c[i]*wi[i]; a1 += h[i]*wh[i]; }
      gis[k] = a0; ghs[k] = a1;
    }
    __syncthreads();
    if (tid < 300){
      float r = sigm(gis[tid] + ghs[tid]);
      float z = sigm(gis[300+tid] + ghs[300+tid]);
      float n = tanh_f(gis[600+tid] + r*ghs[600+tid]);
      h[tid] = (1.f-z)*n + z*h[tid];
    }
    __syncthreads();
  }
}

} // namespace

extern "C" void kernel_launch(void* const* d_in, const int* in_sizes, int n_in,
                              void* d_out, int out_size, void* d_ws, size_t ws_size,
                              hipStream_t stream)
{
  (void)in_sizes; (void)n_in; (void)out_size; (void)ws_size;
  float* ws = (float*)d_ws;
  int* flag = (int*)d_ws;

  static const int wsz[NW] = {
    67500,67500,450,450,
    67500,67500,450,450,
    22500,22500,22500,150,150,1,
    135000,67500,450,450,
    135000,67500,450,450,
    90000,90000,300,
    270000,270000,900,900
  };
  WDesc desc;
  int cum = 0;
  for (int j=0;j<NW;j++){ desc.src[j] = d_in[3+j]; desc.off[j] = cum; cum += wsz[j]; }
  desc.off[NW] = cum;

  float* WB = ws + 16;
  const float* P_ctx_Wih = WB + desc.off[0];
  const float* P_ctx_Whh = WB + desc.off[1];
  const float* P_ctx_bih = WB + desc.off[2];
  const float* P_ctx_bhh = WB + desc.off[3];
  const float* P_q_Wih   = WB + desc.off[4];
  const float* P_q_Whh   = WB + desc.off[5];
  const float* P_q_bih   = WB + desc.off[6];
  const float* P_q_bhh   = WB + desc.off[7];
  const float* P_Wq      = WB + desc.off[8];
  const float* P_Wp      = WB + desc.off[9];
  const float* P_Wr      = WB + desc.off[10];
  const float* P_w       = WB + desc.off[11];
  const float* P_gb      = WB + desc.off[12];
  const float* P_m_Wih   = WB + desc.off[14];
  const float* P_m_Whh   = WB + desc.off[15];
  const float* P_m_bih   = WB + desc.off[16];
  const float* P_m_bhh   = WB + desc.off[17];
  const float* P_mr_Wih  = WB + desc.off[18];
  const float* P_mr_Whh  = WB + desc.off[19];
  const float* P_mr_bih  = WB + desc.off[20];
  const float* P_mr_bhh  = WB + desc.off[21];
  const float* P_W1      = WB + desc.off[22];
  const float* P_W2      = WB + desc.off[23];
  const float* P_pv      = WB + desc.off[24];
  const float* P_dWih    = WB + desc.off[25];
  const float* P_dWhh    = WB + desc.off[26];
  const float* P_dbih    = WB + desc.off[27];
  const float* P_dbhh    = WB + desc.off[28];

  size_t p = 16 + 1468512;
  float* ctxWhhP = ws + p; p += 68400;    // [450][152]
  float* qWhhP   = ws + p; p += 68400;
  float* s2qCtx  = ws + p; p += 21696;    // [12][452] f4
  float* s2qQ    = ws + p; p += 21696;
  float* WcatF   = ws + p; p += 91200;    // [600][152]
  float* WcatR   = ws + p; p += 91200;
  float* s2qF    = ws + p; p += 24576;    // [12][512] f4
  float* s2qR    = ws + p; p += 24576;
  float* extFg   = ws + p; p += 13376;    // [38][88] f4
  float* extRg   = ws + p; p += 13376;
  // transposed input-projection weights (mode-0 layouts)
  float* ctxWihT = ws + p; p += 67500;    // [150][450]
  float* qWihT   = ws + p; p += 67500;
  float* mXfT    = ws + p; p += 67500;    // m_Wih cols 0..149   -> [150][450]
  float* mXrT    = ws + p; p += 67500;
  float* mQfT    = ws + p; p += 67500;    // m_Wih cols 150..299 -> [150][450]
  float* mQrT    = ws + p; p += 67500;

  float* ctx_gi = ws + p; p += 5760000;   // [B,T,450]; reused as enc later
  float* q_gi   = ws + p; p += 432000;    // [B,J,450]
  float* HpB    = ws + p; p += 1920000;   // [B,T,150]
  float* HqB    = ws + p; p += 144000;    // [B,J,150]
  float* whqB   = ws + p; p += 145920;    // [B,J,152]
  float* PfB    = ws + p; p += 433920;    // [B,J,452]
  float* PrB    = ws + p; p += 433920;
  float* pWpB   = ws + p; p += 1945600;   // [B,T,152]
  float* giXfB  = ws + p; p += 5785600;   // [B,T,452]
  float* giXrB  = ws + p; p += 5785600;
  float* HrB    = ws + p; p += 3849600;   // [B,401,300]
  float* encB   = ctx_gi;                 // [B,401,300]

  // 1) dtype sniff + weight conversion + restructured layouts
  sniff_kernel<<<1,256,0,stream>>>((const unsigned int*)d_in[2], flag);
  convert_weights_kernel<<<512,256,0,stream>>>(desc, WB, flag);
  padrows_kernel<<<(450*152+255)/256,256,0,stream>>>(P_ctx_Whh, ctxWhhP, 450,150,152);
  padrows_kernel<<<(450*152+255)/256,256,0,stream>>>(P_q_Whh,   qWhhP,   450,150,152);
  build_gsplit_kernel<<<(12*452*4+255)/256,256,0,stream>>>(ctxWhhP, s2qCtx);
  build_gsplit_kernel<<<(12*452*4+255)/256,256,0,stream>>>(qWhhP,   s2qQ);
  build_wcat_kernel<<<(600*152+255)/256,256,0,stream>>>(P_m_Whh,  P_Wr, WcatF);
  build_wcat_kernel<<<(600*152+255)/256,256,0,stream>>>(P_mr_Whh, P_Wr, WcatR);
  build_msplit_kernel<<<(24576+13376+255)/256,256,0,stream>>>(WcatF, s2qF, extFg);
  build_msplit_kernel<<<(24576+13376+255)/256,256,0,stream>>>(WcatR, s2qR, extRg);
  transpose_kernel<<<(67500+255)/256,256,0,stream>>>(P_ctx_Wih, ctxWihT, 450,150,150,0);
  transpose_kernel<<<(67500+255)/256,256,0,stream>>>(P_q_Wih,   qWihT,   450,150,150,0);
  transpose_kernel<<<(67500+255)/256,256,0,stream>>>(P_m_Wih,   mXfT,    450,150,300,0);
  transpose_kernel<<<(67500+255)/256,256,0,stream>>>(P_mr_Wih,  mXrT,    450,150,300,0);
  transpose_kernel<<<(67500+255)/256,256,0,stream>>>(P_m_Wih,   mQfT,    450,150,300,150);
  transpose_kernel<<<(67500+255)/256,256,0,stream>>>(P_mr_Wih,  mQrT,    450,150,300,150);

  // 2) embedding + input projections for both encoders (mode-0, 16-row tiles)
  rowproj16_kernel<<<800,512,0,stream>>>(nullptr,(const int*)d_in[0], d_in[2], flag,
                                         ctxWihT, P_ctx_bih, ctx_gi, 12800,450,150,450,450);
  rowproj16_kernel<<<60,512,0,stream>>>(nullptr,(const int*)d_in[1], d_in[2], flag,
                                        qWihT, P_q_bih, q_gi, 960,450,150,450,450);

  // 3) encoder scans
  gru_scan_kernel<<<64,512,0,stream>>>(ctx_gi, ctxWhhP, s2qCtx, P_ctx_bhh, HpB, 400,
                                       q_gi,   qWhhP,   s2qQ,   P_q_bhh,   HqB, 30);

  // 4) Hq/Hp-dependent precomputations
  rowproj16_kernel<<<60,512,0,stream>>>(HqB,nullptr,nullptr,nullptr, P_Wq, nullptr,
                                        whqB, 960,150,150,150,152);
  rowproj16_kernel<<<60,512,0,stream>>>(HqB,nullptr,nullptr,nullptr, mQfT, nullptr,
                                        PfB, 960,450,150,450,452);
  rowproj16_kernel<<<60,512,0,stream>>>(HqB,nullptr,nullptr,nullptr, mQrT, nullptr,
                                        PrB, 960,450,150,450,452);
  rowproj16_kernel<<<800,512,0,stream>>>(HpB,nullptr,nullptr,nullptr, P_Wp, P_gb,
                                         pWpB, 12800,150,150,150,152);
  rowproj16_kernel<<<800,512,0,stream>>>(HpB,nullptr,nullptr,nullptr, mXfT, P_m_bih,
                                         giXfB, 12800,450,150,450,452);
  rowproj16_kernel<<<800,512,0,stream>>>(HpB,nullptr,nullptr,nullptr, mXrT, P_mr_bih,
                                         giXrB, 12800,450,150,450,452);

  // 5) match scans (fwd+bwd concurrent)
  zero_hr0_kernel<<<(NBATCH*300+511)/512,512,0,stream>>>(HrB);
  match_scan_kernel<<<dim3(NBATCH,2),512,0,stream>>>(pWpB, whqB, giXfB, giXrB,
                                                     PfB, PrB, WcatF, WcatR,
                                                     s2qF, s2qR, extFg, extRg,
                                                     P_m_bhh, P_mr_bhh, P_w, HrB);

  // 6) pointer decoder
  rowproj16_kernel<<<802,512,0,stream>>>(HrB,nullptr,nullptr,nullptr, P_W1, nullptr,
                                         encB, 12832,300,300,300,300);
  ptr_scan_kernel<<<32,512,0,stream>>>(encB, HrB, P_W2, P_pv,
                                       P_dWih, P_dWhh, P_dbih, P_dbhh, d_out, flag);
}